// Round 1
// baseline (418.520 us; speedup 1.0000x reference)
//
#include <hip/hip_runtime.h>

// ShiftingLayer: out[i + offset] = x[i], offset = trunc(w_row + row_length*w_col).
// Equivalently out[j] = (0 <= j-offset < n) ? x[j-offset] : 0.
// Pure memory-bound shifted copy: 268 MB read + 268 MB write.

__global__ __launch_bounds__(256) void ShiftingLayer_shift_kernel(
    const float* __restrict__ x,
    const float* __restrict__ w_row,
    const float* __restrict__ w_col,
    const int*   __restrict__ row_length,
    float* __restrict__ out,
    long long n)
{
    // Compute the scalar offset on-device (scalars live in 1-element arrays).
    // float->int truncates toward zero, matching numpy astype(int32).
    const long long offset =
        (long long)(int)(w_row[0] + (float)row_length[0] * w_col[0]);

    long long j = ((long long)blockIdx.x * blockDim.x + threadIdx.x) * 4;
    if (j >= n) return;

    const long long s = j - offset;

    float4 v;
    // n is a multiple of 4 (8192*8192), so j..j+3 are all in range for the store.
    v.x = (s + 0 >= 0 && s + 0 < n) ? x[s + 0] : 0.0f;
    v.y = (s + 1 >= 0 && s + 1 < n) ? x[s + 1] : 0.0f;
    v.z = (s + 2 >= 0 && s + 2 < n) ? x[s + 2] : 0.0f;
    v.w = (s + 3 >= 0 && s + 3 < n) ? x[s + 3] : 0.0f;

    *reinterpret_cast<float4*>(out + j) = v;
}

extern "C" void kernel_launch(void* const* d_in, const int* in_sizes, int n_in,
                              void* d_out, int out_size, void* d_ws, size_t ws_size,
                              hipStream_t stream)
{
    const float* x     = (const float*)d_in[0];
    const float* w_row = (const float*)d_in[1];
    const float* w_col = (const float*)d_in[2];
    const int*   rlen  = (const int*)d_in[3];
    float* out = (float*)d_out;

    const long long n = (long long)out_size;  // 67,108,864

    const int block = 256;
    const long long vecs = (n + 3) / 4;
    const int grid = (int)((vecs + block - 1) / block);

    ShiftingLayer_shift_kernel<<<grid, block, 0, stream>>>(
        x, w_row, w_col, rlen, out, n);
}